// Round 4
// baseline (149.589 us; speedup 1.0000x reference)
//
#include <hip/hip_runtime.h>
#include <hip/hip_bf16.h>

typedef __attribute__((ext_vector_type(8))) short short8;
typedef __attribute__((ext_vector_type(4))) float f32x4;

#define NTOK 1024
#define HDIM 1024
#define IDIM 1024
#define NEXP 8
#define NCOL 2048  // 2*I interleaved gate/up

// ---- workspace layout (bytes) ----
#define WS_COUNTS   0
#define WS_OFFSETS  256
#define WS_LTOK     1024
#define WS_LK       (WS_LTOK + NEXP*NTOK*4)
#define WS_LW       (WS_LK + NEXP*NTOK*4)
#define WS_XBF      131072                                   // 1024x1024 bf16 = 2 MB
#define WS_ACT      (WS_XBF + NTOK*HDIM*2)                   // 2048x1024 bf16 = 4 MB
#define WS_TMP      (WS_ACT + 2*NTOK*IDIM*2)                 // 2x1024x1024 f32 = 8 MB

static __device__ __forceinline__ unsigned short f2bf(float x) {
    __hip_bfloat16 h = __float2bfloat16(x);   // RNE
    return __builtin_bit_cast(unsigned short, h);
}

#define GLDS16(g, l) __builtin_amdgcn_global_load_lds( \
    (const __attribute__((address_space(1))) void*)(g), \
    (__attribute__((address_space(3))) void*)(l), 16, 0, 0)

// ---------------- router: logits -> softmax -> top-2 lists; also writes Xbf ----
__global__ __launch_bounds__(64) void router_kernel(
    const float* __restrict__ flat, const float* __restrict__ rw,
    float* __restrict__ scores, int* __restrict__ counts,
    int* __restrict__ ltok, int* __restrict__ lk, float* __restrict__ lw,
    unsigned short* __restrict__ xbf)
{
    const int n = blockIdx.x;
    const int l = threadIdx.x;
    float acc[NEXP];
#pragma unroll
    for (int e = 0; e < NEXP; ++e) acc[e] = 0.f;
    const float* xrow = flat + (size_t)n * HDIM;
#pragma unroll
    for (int j = 0; j < 4; ++j) {
        int h = j * 256 + l * 4;
        float4 v = *(const float4*)&xrow[h];
        ushort4 xb;
        xb.x = f2bf(v.x); xb.y = f2bf(v.y); xb.z = f2bf(v.z); xb.w = f2bf(v.w);
        *(ushort4*)&xbf[(size_t)n * HDIM + h] = xb;
#pragma unroll
        for (int e = 0; e < NEXP; ++e) {
            float4 wv = *(const float4*)&rw[e * HDIM + h];
            acc[e] += v.x * wv.x + v.y * wv.y + v.z * wv.z + v.w * wv.w;
        }
    }
#pragma unroll
    for (int e = 0; e < NEXP; ++e) {
#pragma unroll
        for (int off = 32; off > 0; off >>= 1)
            acc[e] += __shfl_down(acc[e], off);
    }
    if (l == 0) {
        float m = acc[0];
#pragma unroll
        for (int e = 1; e < NEXP; ++e) m = fmaxf(m, acc[e]);
        float s = 0.f, p[NEXP];
#pragma unroll
        for (int e = 0; e < NEXP; ++e) { p[e] = __expf(acc[e] - m); s += p[e]; }
        float inv = 1.f / s;
#pragma unroll
        for (int e = 0; e < NEXP; ++e) { p[e] *= inv; scores[n * NEXP + e] = p[e]; }
        int i0 = 0;
#pragma unroll
        for (int e = 1; e < NEXP; ++e) if (p[e] > p[i0]) i0 = e;
        int i1 = (i0 == 0) ? 1 : 0;
#pragma unroll
        for (int e = 0; e < NEXP; ++e) if (e != i0 && p[e] > p[i1]) i1 = e;
        int pos0 = atomicAdd(&counts[i0], 1);
        ltok[i0 * NTOK + pos0] = n; lk[i0 * NTOK + pos0] = 0; lw[i0 * NTOK + pos0] = p[i0];
        int pos1 = atomicAdd(&counts[i1], 1);
        ltok[i1 * NTOK + pos1] = n; lk[i1 * NTOK + pos1] = 1; lw[i1 * NTOK + pos1] = p[i1];
    }
}

__global__ void scan_kernel(const int* __restrict__ counts, int* __restrict__ offsets) {
    if (threadIdx.x == 0) {
        int acc = 0;
        for (int e = 0; e < NEXP; ++e) { offsets[e] = acc; acc += counts[e]; }
    }
}

// In-register 4x4 transpose across lanes i=0..3 of a group (verified butterfly).
// In: lane i holds M[i][0..3] in v. Out: lane i holds M[0..3][i].
static __device__ __forceinline__ float4 xpose4(float4 v, int i) {
    float x = (i & 1) ? v.x : v.y;
    float y = (i & 1) ? v.z : v.w;
    x = __shfl_xor(x, 1); y = __shfl_xor(y, 1);
    if (i & 1) { v.x = x; v.z = y; } else { v.y = x; v.w = y; }
    float x2 = (i & 2) ? v.x : v.z;
    float y2 = (i & 2) ? v.y : v.w;
    x2 = __shfl_xor(x2, 2); y2 = __shfl_xor(y2, 2);
    if (i & 2) { v.x = x2; v.y = y2; } else { v.z = x2; v.w = y2; }
    return v;
}

// ---------------- GEMM1: act[slot][i] = f(Xbf[tok] @ W1[e]) fused activation ----
// BM=128 slots x BN=128 cols (of 2048), BK=64, 256 thr / 4 waves (2x2).
// A: GLDS16 from xbf (bf16, gathered). B: fp32 [k][col] rows, fused
// transpose+convert in-register -> swizzled LDS (chunk c of row r at c^(r&7)).
__global__ __launch_bounds__(256) void gemm1_kernel(
    const unsigned short* __restrict__ xbf, const float* __restrict__ gup,
    const float* __restrict__ gbias,
    const int* __restrict__ counts, const int* __restrict__ offsets,
    const int* __restrict__ ltok, unsigned short* __restrict__ act)
{
    const int e = blockIdx.z;
    const int cnt = counts[e];
    const int by = blockIdx.y;
    if (by * 128 >= cnt) return;
    const int bx = blockIdx.x;
    const int off = offsets[e];
    const int t = threadIdx.x;
    const int l = t & 63, w = t >> 6;
    const int wm = w >> 1, wn = w & 1;

    __shared__ unsigned short As[2][128][64];
    __shared__ unsigned short Bs[2][128][64];
    __shared__ int toks[128];
    if (t < 128) toks[t] = ltok[e * NTOK + min(by * 128 + t, cnt - 1)];
    __syncthreads();

    // A sources (R3-proven): lane li^lr chunk swizzle, GLDS16 linear dest
    const int li = l & 7, lr = l >> 3;
    const int kswz = (li ^ lr) * 8;
    const unsigned short* asrc[4];
#pragma unroll
    for (int j = 0; j < 4; ++j) {
        int rr = (w * 4 + j) * 8 + lr;
        asrc[j] = xbf + (size_t)toks[rr] * HDIM + kswz;
    }

    // B staging geometry: group g = t>>2 (0..63), lane-in-group i = t&3
    // col quad c4 = ((g>>1)&31)*4, k half kh = (g&1)*4; per it: kbase = it*8+kh
    const int gi = t >> 2, ii = t & 3;
    const int c4 = ((gi >> 1) & 31) * 4;
    const int kh = (gi & 1) * 4;
    const int brow = c4 + ii;                 // LDS row this thread writes
    const int r7 = brow & 7;
    const float* bsrc0 = gup + ((size_t)e * HDIM + kh + ii) * NCOL + bx * 128 + c4;
    unsigned short* bs0 = &Bs[0][0][0];
    unsigned short* bs1 = &Bs[1][0][0];

    f32x4 acc[4][4];
#pragma unroll
    for (int m = 0; m < 4; ++m)
#pragma unroll
        for (int n = 0; n < 4; ++n) acc[m][n] = 0.f;

    float4 breg[8];

    // prologue: stage step 0
#pragma unroll
    for (int it = 0; it < 8; ++it)
        breg[it] = *(const float4*)(bsrc0 + (size_t)(it * 8) * NCOL);
#pragma unroll
    for (int j = 0; j < 4; ++j) GLDS16(asrc[j], &As[0][(w * 4 + j) * 8][0]);
#pragma unroll
    for (int it = 0; it < 8; ++it) {
        float4 v = xpose4(breg[it], ii);
        ushort4 o; o.x = f2bf(v.x); o.y = f2bf(v.y); o.z = f2bf(v.z); o.w = f2bf(v.w);
        *(ushort4*)(bs0 + brow * 64 + ((it ^ r7) << 3) + kh) = o;
    }
    __syncthreads();

    const int lg = l >> 4, lo = l & 15;
    const int cq0 = ((0 + lg) ^ (lo & 7)) * 8;
    const int cq1 = ((4 + lg) ^ (lo & 7)) * 8;

    for (int ks = 0; ks < HDIM / 64; ++ks) {
        const int p = ks & 1;
        if (ks + 1 < HDIM / 64) {
#pragma unroll
            for (int it = 0; it < 8; ++it)
                breg[it] = *(const float4*)(bsrc0 + (size_t)((ks + 1) * 64 + it * 8) * NCOL);
            const int kadv = (ks + 1) * 64;
#pragma unroll
            for (int j = 0; j < 4; ++j)
                GLDS16(asrc[j] + kadv, &As[p ^ 1][(w * 4 + j) * 8][0]);
        }
#pragma unroll
        for (int q = 0; q < 2; ++q) {
            const int cq = q ? cq1 : cq0;
            short8 a0 = *(const short8*)&As[p][wm * 64 +  0 + lo][cq];
            short8 a1 = *(const short8*)&As[p][wm * 64 + 16 + lo][cq];
            short8 a2 = *(const short8*)&As[p][wm * 64 + 32 + lo][cq];
            short8 a3 = *(const short8*)&As[p][wm * 64 + 48 + lo][cq];
            short8 b0 = *(const short8*)&Bs[p][wn * 64 +  0 + lo][cq];
            short8 b1 = *(const short8*)&Bs[p][wn * 64 + 16 + lo][cq];
            short8 b2 = *(const short8*)&Bs[p][wn * 64 + 32 + lo][cq];
            short8 b3 = *(const short8*)&Bs[p][wn * 64 + 48 + lo][cq];
#pragma unroll
            for (int m = 0; m < 4; ++m) {
                short8 am = (m == 0) ? a0 : (m == 1) ? a1 : (m == 2) ? a2 : a3;
                acc[m][0] = __builtin_amdgcn_mfma_f32_16x16x32_bf16(am, b0, acc[m][0], 0, 0, 0);
                acc[m][1] = __builtin_amdgcn_mfma_f32_16x16x32_bf16(am, b1, acc[m][1], 0, 0, 0);
                acc[m][2] = __builtin_amdgcn_mfma_f32_16x16x32_bf16(am, b2, acc[m][2], 0, 0, 0);
                acc[m][3] = __builtin_amdgcn_mfma_f32_16x16x32_bf16(am, b3, acc[m][3], 0, 0, 0);
            }
        }
        if (ks + 1 < HDIM / 64) {
            unsigned short* bsp = (p ^ 1) ? bs1 : bs0;
#pragma unroll
            for (int it = 0; it < 8; ++it) {
                float4 v = xpose4(breg[it], ii);
                ushort4 o; o.x = f2bf(v.x); o.y = f2bf(v.y); o.z = f2bf(v.z); o.w = f2bf(v.w);
                *(ushort4*)(bsp + brow * 64 + ((it ^ r7) << 3) + kh) = o;
            }
        }
        __syncthreads();
    }

    // epilogue: (gate,up) pairs live in adjacent lanes (col parity == lane parity)
    const int rj = lg * 4;
#pragma unroll
    for (int m = 0; m < 4; ++m) {
#pragma unroll
        for (int n = 0; n < 4; ++n) {
            int col = bx * 128 + wn * 64 + n * 16 + lo;
            float bias = gbias[e * NCOL + col];
#pragma unroll
            for (int j = 0; j < 4; ++j) {
                int slot = by * 128 + wm * 64 + m * 16 + rj + j;
                float val = acc[m][n][j] + bias;
                float other = __shfl_xor(val, 1);
                float g = (l & 1) ? other : val;
                float u = (l & 1) ? val : other;
                g = fminf(g, 7.f);
                u = fminf(fmaxf(u, -7.f), 7.f);
                float av = (u + 1.f) * g * (1.f / (1.f + __expf(-1.702f * g)));
                if (!(l & 1) && slot < cnt)
                    act[(size_t)(off + slot) * IDIM + (col >> 1)] = f2bf(av);
            }
        }
    }
}

// ---------------- GEMM2: tmp[k][tok][h] = (act @ W2[e] + bias) * w ----
__global__ __launch_bounds__(256) void gemm2_kernel(
    const unsigned short* __restrict__ act, const float* __restrict__ dp,
    const float* __restrict__ dbias,
    const int* __restrict__ counts, const int* __restrict__ offsets,
    const int* __restrict__ ltok, const int* __restrict__ lkb,
    const float* __restrict__ lw, float* __restrict__ tmp)
{
    const int e = blockIdx.z;
    const int cnt = counts[e];
    const int by = blockIdx.y;
    if (by * 128 >= cnt) return;
    const int bx = blockIdx.x;
    const int off = offsets[e];
    const int t = threadIdx.x;
    const int l = t & 63, w = t >> 6;
    const int wm = w >> 1, wn = w & 1;

    __shared__ unsigned short As[2][128][64];
    __shared__ unsigned short Bs[2][128][64];
    __shared__ int toks[128];
    __shared__ int ksl[128];
    __shared__ float wts[128];
    if (t < 128) {
        int cl = min(by * 128 + t, cnt - 1);
        toks[t] = ltok[e * NTOK + cl];
        ksl[t]  = lkb[e * NTOK + cl];
        wts[t]  = lw[e * NTOK + cl];
    }
    __syncthreads();

    const int li = l & 7, lr = l >> 3;
    const int kswz = (li ^ lr) * 8;
    const unsigned short* asrc[4];
#pragma unroll
    for (int j = 0; j < 4; ++j) {
        int rr = (w * 4 + j) * 8 + lr;
        asrc[j] = act + (size_t)(off + min(by * 128 + rr, cnt - 1)) * IDIM + kswz;
    }

    const int gi = t >> 2, ii = t & 3;
    const int c4 = ((gi >> 1) & 31) * 4;
    const int kh = (gi & 1) * 4;
    const int brow = c4 + ii;
    const int r7 = brow & 7;
    const float* bsrc0 = dp + ((size_t)e * IDIM + kh + ii) * HDIM + bx * 128 + c4;
    unsigned short* bs0 = &Bs[0][0][0];
    unsigned short* bs1 = &Bs[1][0][0];

    f32x4 acc[4][4];
#pragma unroll
    for (int m = 0; m < 4; ++m)
#pragma unroll
        for (int n = 0; n < 4; ++n) acc[m][n] = 0.f;

    float4 breg[8];
#pragma unroll
    for (int it = 0; it < 8; ++it)
        breg[it] = *(const float4*)(bsrc0 + (size_t)(it * 8) * HDIM);
#pragma unroll
    for (int j = 0; j < 4; ++j) GLDS16(asrc[j], &As[0][(w * 4 + j) * 8][0]);
#pragma unroll
    for (int it = 0; it < 8; ++it) {
        float4 v = xpose4(breg[it], ii);
        ushort4 o; o.x = f2bf(v.x); o.y = f2bf(v.y); o.z = f2bf(v.z); o.w = f2bf(v.w);
        *(ushort4*)(bs0 + brow * 64 + ((it ^ r7) << 3) + kh) = o;
    }
    __syncthreads();

    const int lg = l >> 4, lo = l & 15;
    const int cq0 = ((0 + lg) ^ (lo & 7)) * 8;
    const int cq1 = ((4 + lg) ^ (lo & 7)) * 8;

    for (int ks = 0; ks < IDIM / 64; ++ks) {
        const int p = ks & 1;
        if (ks + 1 < IDIM / 64) {
#pragma unroll
            for (int it = 0; it < 8; ++it)
                breg[it] = *(const float4*)(bsrc0 + (size_t)((ks + 1) * 64 + it * 8) * HDIM);
            const int kadv = (ks + 1) * 64;
#pragma unroll
            for (int j = 0; j < 4; ++j)
                GLDS16(asrc[j] + kadv, &As[p ^ 1][(w * 4 + j) * 8][0]);
        }
#pragma unroll
        for (int q = 0; q < 2; ++q) {
            const int cq = q ? cq1 : cq0;
            short8 a0 = *(const short8*)&As[p][wm * 64 +  0 + lo][cq];
            short8 a1 = *(const short8*)&As[p][wm * 64 + 16 + lo][cq];
            short8 a2 = *(const short8*)&As[p][wm * 64 + 32 + lo][cq];
            short8 a3 = *(const short8*)&As[p][wm * 64 + 48 + lo][cq];
            short8 b0 = *(const short8*)&Bs[p][wn * 64 +  0 + lo][cq];
            short8 b1 = *(const short8*)&Bs[p][wn * 64 + 16 + lo][cq];
            short8 b2 = *(const short8*)&Bs[p][wn * 64 + 32 + lo][cq];
            short8 b3 = *(const short8*)&Bs[p][wn * 64 + 48 + lo][cq];
#pragma unroll
            for (int m = 0; m < 4; ++m) {
                short8 am = (m == 0) ? a0 : (m == 1) ? a1 : (m == 2) ? a2 : a3;
                acc[m][0] = __builtin_amdgcn_mfma_f32_16x16x32_bf16(am, b0, acc[m][0], 0, 0, 0);
                acc[m][1] = __builtin_amdgcn_mfma_f32_16x16x32_bf16(am, b1, acc[m][1], 0, 0, 0);
                acc[m][2] = __builtin_amdgcn_mfma_f32_16x16x32_bf16(am, b2, acc[m][2], 0, 0, 0);
                acc[m][3] = __builtin_amdgcn_mfma_f32_16x16x32_bf16(am, b3, acc[m][3], 0, 0, 0);
            }
        }
        if (ks + 1 < IDIM / 64) {
            unsigned short* bsp = (p ^ 1) ? bs1 : bs0;
#pragma unroll
            for (int it = 0; it < 8; ++it) {
                float4 v = xpose4(breg[it], ii);
                ushort4 o; o.x = f2bf(v.x); o.y = f2bf(v.y); o.z = f2bf(v.z); o.w = f2bf(v.w);
                *(ushort4*)(bsp + brow * 64 + ((it ^ r7) << 3) + kh) = o;
            }
        }
        __syncthreads();
    }

    const int rj = lg * 4;
#pragma unroll
    for (int m = 0; m < 4; ++m) {
#pragma unroll
        for (int n = 0; n < 4; ++n) {
            int col = bx * 128 + wn * 64 + n * 16 + lo;
            float bias = dbias[e * HDIM + col];
#pragma unroll
            for (int j = 0; j < 4; ++j) {
                int sl = wm * 64 + m * 16 + rj + j;
                int slot = by * 128 + sl;
                if (slot < cnt) {
                    float val = (acc[m][n][j] + bias) * wts[sl];
                    tmp[((size_t)ksl[sl] * NTOK + toks[sl]) * HDIM + col] = val;
                }
            }
        }
    }
}

// ---------------- combine: out = tmp[0] + tmp[1] ----------------
__global__ __launch_bounds__(256) void combine_kernel(
    const float* __restrict__ tmp, float* __restrict__ out)
{
    int i = blockIdx.x * blockDim.x + threadIdx.x;
    const float4 a = ((const float4*)tmp)[i];
    const float4 b = ((const float4*)(tmp + (size_t)NTOK * HDIM))[i];
    float4 o;
    o.x = a.x + b.x; o.y = a.y + b.y; o.z = a.z + b.z; o.w = a.w + b.w;
    ((float4*)out)[i] = o;
}

extern "C" void kernel_launch(void* const* d_in, const int* in_sizes, int n_in,
                              void* d_out, int out_size, void* d_ws, size_t ws_size,
                              hipStream_t stream) {
    const float* flat  = (const float*)d_in[0];
    const float* rw    = (const float*)d_in[1];
    const float* gup   = (const float*)d_in[2];
    const float* gbias = (const float*)d_in[3];
    const float* dp    = (const float*)d_in[4];
    const float* dbias = (const float*)d_in[5];
    float* out    = (float*)d_out;
    float* scores = out + (size_t)NTOK * HDIM;

    char* ws = (char*)d_ws;
    int*   counts  = (int*)(ws + WS_COUNTS);
    int*   offsets = (int*)(ws + WS_OFFSETS);
    int*   ltok    = (int*)(ws + WS_LTOK);
    int*   lkb     = (int*)(ws + WS_LK);
    float* lw      = (float*)(ws + WS_LW);
    unsigned short* xbf = (unsigned short*)(ws + WS_XBF);
    unsigned short* act = (unsigned short*)(ws + WS_ACT);
    float* tmp     = (float*)(ws + WS_TMP);

    hipMemsetAsync(counts, 0, 32, stream);
    router_kernel<<<NTOK, 64, 0, stream>>>(flat, rw, scores, counts, ltok, lkb, lw, xbf);
    scan_kernel<<<1, 1, 0, stream>>>(counts, offsets);
    gemm1_kernel<<<dim3(16, 8, NEXP), 256, 0, stream>>>(xbf, gup, gbias, counts, offsets, ltok, act);
    gemm2_kernel<<<dim3(8, 8, NEXP), 256, 0, stream>>>(act, dp, dbias, counts, offsets, ltok, lkb, lw, tmp);
    combine_kernel<<<1024, 256, 0, stream>>>(tmp, out);
}

// Round 5
// 113.769 us; speedup vs baseline: 1.3149x; 1.3149x over previous
//
#include <hip/hip_runtime.h>
#include <hip/hip_bf16.h>

typedef __attribute__((ext_vector_type(8))) short short8;
typedef __attribute__((ext_vector_type(4))) float f32x4;

#define NTOK 1024
#define HDIM 1024
#define IDIM 1024
#define NEXP 8
#define NCOL 2048  // 2*I interleaved gate/up

// ---- workspace layout (bytes) ----
#define WS_COUNTS   0
#define WS_OFFSETS  256
#define WS_LTOK     1024
#define WS_LK       (WS_LTOK + NEXP*NTOK*4)
#define WS_LW       (WS_LK + NEXP*NTOK*4)
#define WS_XBF      131072                                   // 1024x1024 bf16 = 2 MB
#define WS_ACT      (WS_XBF + NTOK*HDIM*2)                   // 2048x1024 bf16 = 4 MB
#define WS_TMP      (WS_ACT + 2*NTOK*IDIM*2)                 // 2x1024x1024 f32 = 8 MB
#define WS_W1T      (WS_TMP + 2*NTOK*HDIM*4)                 // 8x2048x1024 bf16 = 32 MB
#define WS_W2T      (WS_W1T + (size_t)NEXP*NCOL*HDIM*2)      // 8x1024x1024 bf16 = 16 MB

static __device__ __forceinline__ unsigned short f2bf(float x) {
    __hip_bfloat16 h = __float2bfloat16(x);   // RNE
    return __builtin_bit_cast(unsigned short, h);
}

#define GLDS16(g, l) __builtin_amdgcn_global_load_lds( \
    (const __attribute__((address_space(1))) void*)(g), \
    (__attribute__((address_space(3))) void*)(l), 16, 0, 0)

// ---------------- router: logits -> softmax -> top-2 lists; also writes Xbf ----
__global__ __launch_bounds__(64) void router_kernel(
    const float* __restrict__ flat, const float* __restrict__ rw,
    float* __restrict__ scores, int* __restrict__ counts,
    int* __restrict__ ltok, int* __restrict__ lk, float* __restrict__ lw,
    unsigned short* __restrict__ xbf)
{
    const int n = blockIdx.x;
    const int l = threadIdx.x;
    float acc[NEXP];
#pragma unroll
    for (int e = 0; e < NEXP; ++e) acc[e] = 0.f;
    const float* xrow = flat + (size_t)n * HDIM;
#pragma unroll
    for (int j = 0; j < 4; ++j) {
        int h = j * 256 + l * 4;
        float4 v = *(const float4*)&xrow[h];
        ushort4 xb;
        xb.x = f2bf(v.x); xb.y = f2bf(v.y); xb.z = f2bf(v.z); xb.w = f2bf(v.w);
        *(ushort4*)&xbf[(size_t)n * HDIM + h] = xb;
#pragma unroll
        for (int e = 0; e < NEXP; ++e) {
            float4 wv = *(const float4*)&rw[e * HDIM + h];
            acc[e] += v.x * wv.x + v.y * wv.y + v.z * wv.z + v.w * wv.w;
        }
    }
#pragma unroll
    for (int e = 0; e < NEXP; ++e) {
#pragma unroll
        for (int off = 32; off > 0; off >>= 1)
            acc[e] += __shfl_down(acc[e], off);
    }
    if (l == 0) {
        float m = acc[0];
#pragma unroll
        for (int e = 1; e < NEXP; ++e) m = fmaxf(m, acc[e]);
        float s = 0.f, p[NEXP];
#pragma unroll
        for (int e = 0; e < NEXP; ++e) { p[e] = __expf(acc[e] - m); s += p[e]; }
        float inv = 1.f / s;
#pragma unroll
        for (int e = 0; e < NEXP; ++e) { p[e] *= inv; scores[n * NEXP + e] = p[e]; }
        int i0 = 0;
#pragma unroll
        for (int e = 1; e < NEXP; ++e) if (p[e] > p[i0]) i0 = e;
        int i1 = (i0 == 0) ? 1 : 0;
#pragma unroll
        for (int e = 0; e < NEXP; ++e) if (e != i0 && p[e] > p[i1]) i1 = e;
        int pos0 = atomicAdd(&counts[i0], 1);
        ltok[i0 * NTOK + pos0] = n; lk[i0 * NTOK + pos0] = 0; lw[i0 * NTOK + pos0] = p[i0];
        int pos1 = atomicAdd(&counts[i1], 1);
        ltok[i1 * NTOK + pos1] = n; lk[i1 * NTOK + pos1] = 1; lw[i1 * NTOK + pos1] = p[i1];
    }
}

__global__ void scan_kernel(const int* __restrict__ counts, int* __restrict__ offsets) {
    if (threadIdx.x == 0) {
        int acc = 0;
        for (int e = 0; e < NEXP; ++e) { offsets[e] = acc; acc += counts[e]; }
    }
}

// ---------------- fused convert fp32 -> bf16 + transpose per expert ----
// src[e][nrows][ncols] (f32) -> dst[e][ncols][nrows] (bf16). grid(ncols/64, nrows/64, E)
__global__ __launch_bounds__(256) void transpose_bf16_kernel(
    const float* __restrict__ src, unsigned short* __restrict__ dst,
    int nrows, int ncols)
{
    const int e = blockIdx.z, rb = blockIdx.y, cb = blockIdx.x;
    __shared__ float tile[64][65];
    const int t = threadIdx.x;
    {
        const int r0 = t >> 4, c4 = (t & 15) * 4;
#pragma unroll
        for (int p = 0; p < 4; ++p) {
            int r = p * 16 + r0;
            float4 v = *(const float4*)&src[((size_t)e * nrows + rb * 64 + r) * ncols + cb * 64 + c4];
            tile[r][c4 + 0] = v.x; tile[r][c4 + 1] = v.y;
            tile[r][c4 + 2] = v.z; tile[r][c4 + 3] = v.w;
        }
    }
    __syncthreads();
    {
        const int c0 = t >> 3, r8 = (t & 7) * 8;
#pragma unroll
        for (int p = 0; p < 2; ++p) {
            int c = p * 32 + c0;
            short8 o;
#pragma unroll
            for (int i = 0; i < 8; ++i) o[i] = (short)f2bf(tile[r8 + i][c]);
            *(short8*)&dst[((size_t)e * ncols + cb * 64 + c) * nrows + rb * 64 + r8] = o;
        }
    }
}

// ---------------- GEMM1: act[slot][i] = f(Xbf[tok] @ W1t[e]) fused activation ----
// BM=128 x BN=128, BK=64, 512 thr / 8 waves (2 row-halves x 4 col-quads),
// wave-tile 64x32 (acc 4x2). 2 waves/SIMD for latency overlap.
__global__ __launch_bounds__(512) void gemm1_kernel(
    const unsigned short* __restrict__ xbf, const unsigned short* __restrict__ w1t,
    const float* __restrict__ gbias,
    const int* __restrict__ counts, const int* __restrict__ offsets,
    const int* __restrict__ ltok, unsigned short* __restrict__ act)
{
    const int e = blockIdx.z;
    const int cnt = counts[e];
    const int by = blockIdx.y;
    if (by * 128 >= cnt) return;
    const int bx = blockIdx.x;
    const int off = offsets[e];
    const int t = threadIdx.x;
    const int l = t & 63, w = t >> 6;
    const int wm = w >> 2, wn = w & 3;

    __shared__ unsigned short As[2][128][64];
    __shared__ unsigned short Bs[2][128][64];
    __shared__ int toks[128];
    if (t < 128) toks[t] = ltok[e * NTOK + min(by * 128 + t, cnt - 1)];
    __syncthreads();

    // wave w stages A rows [w*16, w*16+16) and B rows likewise: 2+2 GLDS16/step
    const int li = l & 7, lr = l >> 3;
    const int kswz = (li ^ lr) * 8;
    const unsigned short* asrc[2];
    const unsigned short* bsrc[2];
#pragma unroll
    for (int j = 0; j < 2; ++j) {
        int rr = (w * 2 + j) * 8 + lr;
        asrc[j] = xbf + (size_t)toks[rr] * HDIM + kswz;
        bsrc[j] = w1t + ((size_t)e * NCOL + bx * 128 + rr) * HDIM + kswz;
    }

    f32x4 acc[4][2];
#pragma unroll
    for (int m = 0; m < 4; ++m)
#pragma unroll
        for (int n = 0; n < 2; ++n) acc[m][n] = 0.f;

#pragma unroll
    for (int j = 0; j < 2; ++j) {
        GLDS16(asrc[j], &As[0][(w * 2 + j) * 8][0]);
        GLDS16(bsrc[j], &Bs[0][(w * 2 + j) * 8][0]);
    }
    __syncthreads();

    const int lg = l >> 4, lo = l & 15;
    const int cq0 = ((0 + lg) ^ (lo & 7)) * 8;
    const int cq1 = ((4 + lg) ^ (lo & 7)) * 8;

    for (int ks = 0; ks < HDIM / 64; ++ks) {
        const int p = ks & 1;
        if (ks + 1 < HDIM / 64) {
            const int kadv = (ks + 1) * 64;
#pragma unroll
            for (int j = 0; j < 2; ++j) {
                GLDS16(asrc[j] + kadv, &As[p ^ 1][(w * 2 + j) * 8][0]);
                GLDS16(bsrc[j] + kadv, &Bs[p ^ 1][(w * 2 + j) * 8][0]);
            }
        }
#pragma unroll
        for (int q = 0; q < 2; ++q) {
            const int cq = q ? cq1 : cq0;
            short8 a0 = *(const short8*)&As[p][wm * 64 +  0 + lo][cq];
            short8 a1 = *(const short8*)&As[p][wm * 64 + 16 + lo][cq];
            short8 a2 = *(const short8*)&As[p][wm * 64 + 32 + lo][cq];
            short8 a3 = *(const short8*)&As[p][wm * 64 + 48 + lo][cq];
            short8 b0 = *(const short8*)&Bs[p][wn * 32 +  0 + lo][cq];
            short8 b1 = *(const short8*)&Bs[p][wn * 32 + 16 + lo][cq];
#pragma unroll
            for (int m = 0; m < 4; ++m) {
                short8 am = (m == 0) ? a0 : (m == 1) ? a1 : (m == 2) ? a2 : a3;
                acc[m][0] = __builtin_amdgcn_mfma_f32_16x16x32_bf16(am, b0, acc[m][0], 0, 0, 0);
                acc[m][1] = __builtin_amdgcn_mfma_f32_16x16x32_bf16(am, b1, acc[m][1], 0, 0, 0);
            }
        }
        __syncthreads();
    }

    // epilogue: (gate,up) pairs live in adjacent lanes (col parity == lane parity)
    const int rj = lg * 4;
#pragma unroll
    for (int m = 0; m < 4; ++m) {
#pragma unroll
        for (int n = 0; n < 2; ++n) {
            int col = bx * 128 + wn * 32 + n * 16 + lo;
            float bias = gbias[e * NCOL + col];
#pragma unroll
            for (int j = 0; j < 4; ++j) {
                int slot = by * 128 + wm * 64 + m * 16 + rj + j;
                float val = acc[m][n][j] + bias;
                float other = __shfl_xor(val, 1);
                float g = (l & 1) ? other : val;
                float u = (l & 1) ? val : other;
                g = fminf(g, 7.f);
                u = fminf(fmaxf(u, -7.f), 7.f);
                float av = (u + 1.f) * g * (1.f / (1.f + __expf(-1.702f * g)));
                if (!(l & 1) && slot < cnt)
                    act[(size_t)(off + slot) * IDIM + (col >> 1)] = f2bf(av);
            }
        }
    }
}

// ---------------- GEMM2: tmp[k][tok][h] = (act @ W2t[e] + bias) * w ----
// BM=128 x BN=64, BK=64, 512 thr / 8 waves (4x2), wave-tile 32x32 (acc 2x2)
__global__ __launch_bounds__(512) void gemm2_kernel(
    const unsigned short* __restrict__ act, const unsigned short* __restrict__ w2t,
    const float* __restrict__ dbias,
    const int* __restrict__ counts, const int* __restrict__ offsets,
    const int* __restrict__ ltok, const int* __restrict__ lkb,
    const float* __restrict__ lw, float* __restrict__ tmp)
{
    const int e = blockIdx.z;
    const int cnt = counts[e];
    const int by = blockIdx.y;
    if (by * 128 >= cnt) return;
    const int bx = blockIdx.x;
    const int off = offsets[e];
    const int t = threadIdx.x;
    const int l = t & 63, w = t >> 6;
    const int wm = w >> 1, wn = w & 1;

    __shared__ unsigned short As[2][128][64];
    __shared__ unsigned short Bs[2][64][64];
    __shared__ int toks[128];
    __shared__ int ksl[128];
    __shared__ float wts[128];
    if (t < 128) {
        int cl = min(by * 128 + t, cnt - 1);
        toks[t] = ltok[e * NTOK + cl];
        ksl[t]  = lkb[e * NTOK + cl];
        wts[t]  = lw[e * NTOK + cl];
    }
    __syncthreads();

    // wave w stages A rows [w*16, w*16+16) (2 loads) and B rows [w*8, w*8+8) (1 load)
    const int li = l & 7, lr = l >> 3;
    const int kswz = (li ^ lr) * 8;
    const unsigned short* asrc[2];
#pragma unroll
    for (int j = 0; j < 2; ++j) {
        int rr = (w * 2 + j) * 8 + lr;
        asrc[j] = act + (size_t)(off + min(by * 128 + rr, cnt - 1)) * IDIM + kswz;
    }
    const unsigned short* bsrc = w2t + ((size_t)e * HDIM + bx * 64 + w * 8 + lr) * IDIM + kswz;

    f32x4 acc[2][2];
#pragma unroll
    for (int m = 0; m < 2; ++m)
#pragma unroll
        for (int n = 0; n < 2; ++n) acc[m][n] = 0.f;

#pragma unroll
    for (int j = 0; j < 2; ++j)
        GLDS16(asrc[j], &As[0][(w * 2 + j) * 8][0]);
    GLDS16(bsrc, &Bs[0][w * 8][0]);
    __syncthreads();

    const int lg = l >> 4, lo = l & 15;
    const int cq0 = ((0 + lg) ^ (lo & 7)) * 8;
    const int cq1 = ((4 + lg) ^ (lo & 7)) * 8;

    for (int ks = 0; ks < IDIM / 64; ++ks) {
        const int p = ks & 1;
        if (ks + 1 < IDIM / 64) {
            const int kadv = (ks + 1) * 64;
#pragma unroll
            for (int j = 0; j < 2; ++j)
                GLDS16(asrc[j] + kadv, &As[p ^ 1][(w * 2 + j) * 8][0]);
            GLDS16(bsrc + kadv, &Bs[p ^ 1][w * 8][0]);
        }
#pragma unroll
        for (int q = 0; q < 2; ++q) {
            const int cq = q ? cq1 : cq0;
            short8 a0 = *(const short8*)&As[p][wm * 32 +  0 + lo][cq];
            short8 a1 = *(const short8*)&As[p][wm * 32 + 16 + lo][cq];
            short8 b0 = *(const short8*)&Bs[p][wn * 32 +  0 + lo][cq];
            short8 b1 = *(const short8*)&Bs[p][wn * 32 + 16 + lo][cq];
            acc[0][0] = __builtin_amdgcn_mfma_f32_16x16x32_bf16(a0, b0, acc[0][0], 0, 0, 0);
            acc[1][0] = __builtin_amdgcn_mfma_f32_16x16x32_bf16(a1, b0, acc[1][0], 0, 0, 0);
            acc[0][1] = __builtin_amdgcn_mfma_f32_16x16x32_bf16(a0, b1, acc[0][1], 0, 0, 0);
            acc[1][1] = __builtin_amdgcn_mfma_f32_16x16x32_bf16(a1, b1, acc[1][1], 0, 0, 0);
        }
        __syncthreads();
    }

    const int rj = lg * 4;
#pragma unroll
    for (int m = 0; m < 2; ++m) {
#pragma unroll
        for (int n = 0; n < 2; ++n) {
            int col = bx * 64 + wn * 32 + n * 16 + lo;
            float bias = dbias[e * HDIM + col];
#pragma unroll
            for (int j = 0; j < 4; ++j) {
                int sl = wm * 32 + m * 16 + rj + j;
                int slot = by * 128 + sl;
                if (slot < cnt) {
                    float val = (acc[m][n][j] + bias) * wts[sl];
                    tmp[((size_t)ksl[sl] * NTOK + toks[sl]) * HDIM + col] = val;
                }
            }
        }
    }
}

// ---------------- combine: out = tmp[0] + tmp[1] ----------------
__global__ __launch_bounds__(256) void combine_kernel(
    const float* __restrict__ tmp, float* __restrict__ out)
{
    int i = blockIdx.x * blockDim.x + threadIdx.x;
    const float4 a = ((const float4*)tmp)[i];
    const float4 b = ((const float4*)(tmp + (size_t)NTOK * HDIM))[i];
    float4 o;
    o.x = a.x + b.x; o.y = a.y + b.y; o.z = a.z + b.z; o.w = a.w + b.w;
    ((float4*)out)[i] = o;
}

extern "C" void kernel_launch(void* const* d_in, const int* in_sizes, int n_in,
                              void* d_out, int out_size, void* d_ws, size_t ws_size,
                              hipStream_t stream) {
    const float* flat  = (const float*)d_in[0];
    const float* rw    = (const float*)d_in[1];
    const float* gup   = (const float*)d_in[2];
    const float* gbias = (const float*)d_in[3];
    const float* dp    = (const float*)d_in[4];
    const float* dbias = (const float*)d_in[5];
    float* out    = (float*)d_out;
    float* scores = out + (size_t)NTOK * HDIM;

    char* ws = (char*)d_ws;
    int*   counts  = (int*)(ws + WS_COUNTS);
    int*   offsets = (int*)(ws + WS_OFFSETS);
    int*   ltok    = (int*)(ws + WS_LTOK);
    int*   lkb     = (int*)(ws + WS_LK);
    float* lw      = (float*)(ws + WS_LW);
    unsigned short* xbf = (unsigned short*)(ws + WS_XBF);
    unsigned short* act = (unsigned short*)(ws + WS_ACT);
    float* tmp     = (float*)(ws + WS_TMP);
    unsigned short* w1t = (unsigned short*)(ws + WS_W1T);
    unsigned short* w2t = (unsigned short*)(ws + WS_W2T);

    hipMemsetAsync(counts, 0, 32, stream);
    router_kernel<<<NTOK, 64, 0, stream>>>(flat, rw, scores, counts, ltok, lkb, lw, xbf);
    scan_kernel<<<1, 1, 0, stream>>>(counts, offsets);
    transpose_bf16_kernel<<<dim3(NCOL / 64, HDIM / 64, NEXP), 256, 0, stream>>>(gup, w1t, HDIM, NCOL);
    transpose_bf16_kernel<<<dim3(HDIM / 64, IDIM / 64, NEXP), 256, 0, stream>>>(dp, w2t, IDIM, HDIM);
    gemm1_kernel<<<dim3(16, 8, NEXP), 512, 0, stream>>>(xbf, w1t, gbias, counts, offsets, ltok, act);
    gemm2_kernel<<<dim3(16, 8, NEXP), 512, 0, stream>>>(act, w2t, dbias, counts, offsets, ltok, lkb, lw, tmp);
    combine_kernel<<<1024, 256, 0, stream>>>(tmp, out);
}

// Round 6
// 106.082 us; speedup vs baseline: 1.4101x; 1.0725x over previous
//
#include <hip/hip_runtime.h>
#include <hip/hip_bf16.h>

typedef __attribute__((ext_vector_type(8))) short short8;
typedef __attribute__((ext_vector_type(4))) float f32x4;

#define NTOK 1024
#define HDIM 1024
#define IDIM 1024
#define NEXP 8
#define NCOL 2048  // 2*I interleaved gate/up

// ---- workspace layout (bytes) ----
#define WS_COUNTS   0
#define WS_LTOK     1024
#define WS_LK       (WS_LTOK + NEXP*NTOK*4)
#define WS_LW       (WS_LK + NEXP*NTOK*4)
#define WS_XBF      131072                                   // 1024x1024 bf16 = 2 MB
#define WS_ACT      (WS_XBF + NTOK*HDIM*2)                   // 2048x1024 bf16 = 4 MB
#define WS_TMP      (WS_ACT + 2*NTOK*IDIM*2)                 // 2x1024x1024 f32 = 8 MB
#define WS_W1T      (WS_TMP + 2*NTOK*HDIM*4)                 // 8x2048x1024 bf16 = 32 MB
#define WS_W2T      (WS_W1T + (size_t)NEXP*NCOL*HDIM*2)      // 8x1024x1024 bf16 = 16 MB

static __device__ __forceinline__ unsigned short f2bf(float x) {
    __hip_bfloat16 h = __float2bfloat16(x);   // RNE
    return __builtin_bit_cast(unsigned short, h);
}

#define GLDS16(g, l) __builtin_amdgcn_global_load_lds( \
    (const __attribute__((address_space(1))) void*)(g), \
    (__attribute__((address_space(3))) void*)(l), 16, 0, 0)

// ---------------- router: logits -> softmax -> top-2 lists; also writes Xbf ----
__global__ __launch_bounds__(64) void router_kernel(
    const float* __restrict__ flat, const float* __restrict__ rw,
    float* __restrict__ scores, int* __restrict__ counts,
    int* __restrict__ ltok, int* __restrict__ lk, float* __restrict__ lw,
    unsigned short* __restrict__ xbf)
{
    const int n = blockIdx.x;
    const int l = threadIdx.x;
    float acc[NEXP];
#pragma unroll
    for (int e = 0; e < NEXP; ++e) acc[e] = 0.f;
    const float* xrow = flat + (size_t)n * HDIM;
#pragma unroll
    for (int j = 0; j < 4; ++j) {
        int h = j * 256 + l * 4;
        float4 v = *(const float4*)&xrow[h];
        ushort4 xb;
        xb.x = f2bf(v.x); xb.y = f2bf(v.y); xb.z = f2bf(v.z); xb.w = f2bf(v.w);
        *(ushort4*)&xbf[(size_t)n * HDIM + h] = xb;
#pragma unroll
        for (int e = 0; e < NEXP; ++e) {
            float4 wv = *(const float4*)&rw[e * HDIM + h];
            acc[e] += v.x * wv.x + v.y * wv.y + v.z * wv.z + v.w * wv.w;
        }
    }
#pragma unroll
    for (int e = 0; e < NEXP; ++e) {
#pragma unroll
        for (int off = 32; off > 0; off >>= 1)
            acc[e] += __shfl_down(acc[e], off);
    }
    if (l == 0) {
        float m = acc[0];
#pragma unroll
        for (int e = 1; e < NEXP; ++e) m = fmaxf(m, acc[e]);
        float s = 0.f, p[NEXP];
#pragma unroll
        for (int e = 0; e < NEXP; ++e) { p[e] = __expf(acc[e] - m); s += p[e]; }
        float inv = 1.f / s;
#pragma unroll
        for (int e = 0; e < NEXP; ++e) { p[e] *= inv; scores[n * NEXP + e] = p[e]; }
        int i0 = 0;
#pragma unroll
        for (int e = 1; e < NEXP; ++e) if (p[e] > p[i0]) i0 = e;
        int i1 = (i0 == 0) ? 1 : 0;
#pragma unroll
        for (int e = 0; e < NEXP; ++e) if (e != i0 && p[e] > p[i1]) i1 = e;
        int pos0 = atomicAdd(&counts[i0], 1);
        ltok[i0 * NTOK + pos0] = n; lk[i0 * NTOK + pos0] = 0; lw[i0 * NTOK + pos0] = p[i0];
        int pos1 = atomicAdd(&counts[i1], 1);
        ltok[i1 * NTOK + pos1] = n; lk[i1 * NTOK + pos1] = 1; lw[i1 * NTOK + pos1] = p[i1];
    }
}

// ---------------- fused convert fp32 -> bf16 + transpose per expert ----
// src[e][nrows][ncols] (f32) -> dst[e][ncols][nrows] (bf16). grid(ncols/64, nrows/64, E)
__global__ __launch_bounds__(256) void transpose_bf16_kernel(
    const float* __restrict__ src, unsigned short* __restrict__ dst,
    int nrows, int ncols)
{
    const int e = blockIdx.z, rb = blockIdx.y, cb = blockIdx.x;
    __shared__ float tile[64][65];
    const int t = threadIdx.x;
    {
        const int r0 = t >> 4, c4 = (t & 15) * 4;
#pragma unroll
        for (int p = 0; p < 4; ++p) {
            int r = p * 16 + r0;
            float4 v = *(const float4*)&src[((size_t)e * nrows + rb * 64 + r) * ncols + cb * 64 + c4];
            tile[r][c4 + 0] = v.x; tile[r][c4 + 1] = v.y;
            tile[r][c4 + 2] = v.z; tile[r][c4 + 3] = v.w;
        }
    }
    __syncthreads();
    {
        const int c0 = t >> 3, r8 = (t & 7) * 8;
#pragma unroll
        for (int p = 0; p < 2; ++p) {
            int c = p * 32 + c0;
            short8 o;
#pragma unroll
            for (int i = 0; i < 8; ++i) o[i] = (short)f2bf(tile[r8 + i][c]);
            *(short8*)&dst[((size_t)e * ncols + cb * 64 + c) * nrows + rb * 64 + r8] = o;
        }
    }
}

// ---------------- GEMM1: act[slot][i] = f(Xbf[tok] @ W1t[e]) fused activation ----
// BM=128 x BN=128, BK=64, 512 thr / 8 waves (2x4), wave-tile 64x32 (acc 4x2).
// K-loop: two raw barriers + counted vmcnt (loads for t+1 never drained).
__global__ __launch_bounds__(512) void gemm1_kernel(
    const unsigned short* __restrict__ xbf, const unsigned short* __restrict__ w1t,
    const float* __restrict__ gbias,
    const int* __restrict__ counts,
    const int* __restrict__ ltok, unsigned short* __restrict__ act)
{
    const int e = blockIdx.z;
    int cnt = 0, off = 0;
#pragma unroll
    for (int j2 = 0; j2 < NEXP; ++j2) {
        int c = counts[j2];
        if (j2 < e) off += c;
        if (j2 == e) cnt = c;
    }
    const int by = blockIdx.y;
    if (by * 128 >= cnt) return;
    const int bx = blockIdx.x;
    const int t = threadIdx.x;
    const int l = t & 63, w = t >> 6;
    const int wm = w >> 2, wn = w & 3;

    __shared__ unsigned short As[2][128][64];
    __shared__ unsigned short Bs[2][128][64];
    __shared__ int toks[128];
    if (t < 128) toks[t] = ltok[e * NTOK + min(by * 128 + t, cnt - 1)];
    __syncthreads();

    const int li = l & 7, lr = l >> 3;
    const int kswz = (li ^ lr) * 8;
    const unsigned short* asrc[2];
    const unsigned short* bsrc[2];
#pragma unroll
    for (int j = 0; j < 2; ++j) {
        int rr = (w * 2 + j) * 8 + lr;
        asrc[j] = xbf + (size_t)toks[rr] * HDIM + kswz;
        bsrc[j] = w1t + ((size_t)e * NCOL + bx * 128 + rr) * HDIM + kswz;
    }

    f32x4 acc[4][2];
#pragma unroll
    for (int m = 0; m < 4; ++m)
#pragma unroll
        for (int n = 0; n < 2; ++n) acc[m][n] = 0.f;

    // prologue: issue loads(0)
#pragma unroll
    for (int j = 0; j < 2; ++j) {
        GLDS16(asrc[j], &As[0][(w * 2 + j) * 8][0]);
        GLDS16(bsrc[j], &Bs[0][(w * 2 + j) * 8][0]);
    }

    const int lg = l >> 4, lo = l & 15;
    const int cq0 = ((0 + lg) ^ (lo & 7)) * 8;
    const int cq1 = ((4 + lg) ^ (lo & 7)) * 8;

    for (int ks = 0; ks < HDIM / 64; ++ks) {
        const int p = ks & 1;
        __builtin_amdgcn_s_barrier();     // closes compute(ks-1): back buffer free
        if (ks + 1 < HDIM / 64) {
            const int kadv = (ks + 1) * 64;
#pragma unroll
            for (int j = 0; j < 2; ++j) {
                GLDS16(asrc[j] + kadv, &As[p ^ 1][(w * 2 + j) * 8][0]);
                GLDS16(bsrc[j] + kadv, &Bs[p ^ 1][(w * 2 + j) * 8][0]);
            }
            asm volatile("s_waitcnt vmcnt(4)" ::: "memory");  // own ks-loads done; ks+1 in flight
        } else {
            asm volatile("s_waitcnt vmcnt(0)" ::: "memory");
        }
        __builtin_amdgcn_sched_barrier(0);
        __builtin_amdgcn_s_barrier();     // all waves' ks-loads visible
#pragma unroll
        for (int q = 0; q < 2; ++q) {
            const int cq = q ? cq1 : cq0;
            short8 a0 = *(const short8*)&As[p][wm * 64 +  0 + lo][cq];
            short8 a1 = *(const short8*)&As[p][wm * 64 + 16 + lo][cq];
            short8 a2 = *(const short8*)&As[p][wm * 64 + 32 + lo][cq];
            short8 a3 = *(const short8*)&As[p][wm * 64 + 48 + lo][cq];
            short8 b0 = *(const short8*)&Bs[p][wn * 32 +  0 + lo][cq];
            short8 b1 = *(const short8*)&Bs[p][wn * 32 + 16 + lo][cq];
#pragma unroll
            for (int m = 0; m < 4; ++m) {
                short8 am = (m == 0) ? a0 : (m == 1) ? a1 : (m == 2) ? a2 : a3;
                acc[m][0] = __builtin_amdgcn_mfma_f32_16x16x32_bf16(am, b0, acc[m][0], 0, 0, 0);
                acc[m][1] = __builtin_amdgcn_mfma_f32_16x16x32_bf16(am, b1, acc[m][1], 0, 0, 0);
            }
        }
    }

    // epilogue: (gate,up) pairs live in adjacent lanes (col parity == lane parity)
    const int rj = lg * 4;
#pragma unroll
    for (int m = 0; m < 4; ++m) {
#pragma unroll
        for (int n = 0; n < 2; ++n) {
            int col = bx * 128 + wn * 32 + n * 16 + lo;
            float bias = gbias[e * NCOL + col];
#pragma unroll
            for (int j = 0; j < 4; ++j) {
                int slot = by * 128 + wm * 64 + m * 16 + rj + j;
                float val = acc[m][n][j] + bias;
                float other = __shfl_xor(val, 1);
                float g = (l & 1) ? other : val;
                float u = (l & 1) ? val : other;
                g = fminf(g, 7.f);
                u = fminf(fmaxf(u, -7.f), 7.f);
                float av = (u + 1.f) * g * (1.f / (1.f + __expf(-1.702f * g)));
                if (!(l & 1) && slot < cnt)
                    act[(size_t)(off + slot) * IDIM + (col >> 1)] = f2bf(av);
            }
        }
    }
}

// ---------------- GEMM2: tmp[k][tok][h] = (act @ W2t[e] + bias) * w ----
// BM=128 x BN=64, BK=64, 512 thr / 8 waves (4x2), wave-tile 32x32 (acc 2x2)
__global__ __launch_bounds__(512) void gemm2_kernel(
    const unsigned short* __restrict__ act, const unsigned short* __restrict__ w2t,
    const float* __restrict__ dbias,
    const int* __restrict__ counts,
    const int* __restrict__ ltok, const int* __restrict__ lkb,
    const float* __restrict__ lw, float* __restrict__ tmp)
{
    const int e = blockIdx.z;
    int cnt = 0, off = 0;
#pragma unroll
    for (int j2 = 0; j2 < NEXP; ++j2) {
        int c = counts[j2];
        if (j2 < e) off += c;
        if (j2 == e) cnt = c;
    }
    const int by = blockIdx.y;
    if (by * 128 >= cnt) return;
    const int bx = blockIdx.x;
    const int t = threadIdx.x;
    const int l = t & 63, w = t >> 6;
    const int wm = w >> 1, wn = w & 1;

    __shared__ unsigned short As[2][128][64];
    __shared__ unsigned short Bs[2][64][64];
    __shared__ int toks[128];
    __shared__ int ksl[128];
    __shared__ float wts[128];
    if (t < 128) {
        int cl = min(by * 128 + t, cnt - 1);
        toks[t] = ltok[e * NTOK + cl];
        ksl[t]  = lkb[e * NTOK + cl];
        wts[t]  = lw[e * NTOK + cl];
    }
    __syncthreads();

    const int li = l & 7, lr = l >> 3;
    const int kswz = (li ^ lr) * 8;
    const unsigned short* asrc[2];
#pragma unroll
    for (int j = 0; j < 2; ++j) {
        int rr = (w * 2 + j) * 8 + lr;
        asrc[j] = act + (size_t)(off + min(by * 128 + rr, cnt - 1)) * IDIM + kswz;
    }
    const unsigned short* bsrc = w2t + ((size_t)e * HDIM + bx * 64 + w * 8 + lr) * IDIM + kswz;

    f32x4 acc[2][2];
#pragma unroll
    for (int m = 0; m < 2; ++m)
#pragma unroll
        for (int n = 0; n < 2; ++n) acc[m][n] = 0.f;

    // prologue: issue loads(0)
#pragma unroll
    for (int j = 0; j < 2; ++j)
        GLDS16(asrc[j], &As[0][(w * 2 + j) * 8][0]);
    GLDS16(bsrc, &Bs[0][w * 8][0]);

    const int lg = l >> 4, lo = l & 15;
    const int cq0 = ((0 + lg) ^ (lo & 7)) * 8;
    const int cq1 = ((4 + lg) ^ (lo & 7)) * 8;

    for (int ks = 0; ks < IDIM / 64; ++ks) {
        const int p = ks & 1;
        __builtin_amdgcn_s_barrier();
        if (ks + 1 < IDIM / 64) {
            const int kadv = (ks + 1) * 64;
#pragma unroll
            for (int j = 0; j < 2; ++j)
                GLDS16(asrc[j] + kadv, &As[p ^ 1][(w * 2 + j) * 8][0]);
            GLDS16(bsrc + kadv, &Bs[p ^ 1][w * 8][0]);
            asm volatile("s_waitcnt vmcnt(3)" ::: "memory");
        } else {
            asm volatile("s_waitcnt vmcnt(0)" ::: "memory");
        }
        __builtin_amdgcn_sched_barrier(0);
        __builtin_amdgcn_s_barrier();
#pragma unroll
        for (int q = 0; q < 2; ++q) {
            const int cq = q ? cq1 : cq0;
            short8 a0 = *(const short8*)&As[p][wm * 32 +  0 + lo][cq];
            short8 a1 = *(const short8*)&As[p][wm * 32 + 16 + lo][cq];
            short8 b0 = *(const short8*)&Bs[p][wn * 32 +  0 + lo][cq];
            short8 b1 = *(const short8*)&Bs[p][wn * 32 + 16 + lo][cq];
            acc[0][0] = __builtin_amdgcn_mfma_f32_16x16x32_bf16(a0, b0, acc[0][0], 0, 0, 0);
            acc[1][0] = __builtin_amdgcn_mfma_f32_16x16x32_bf16(a1, b0, acc[1][0], 0, 0, 0);
            acc[0][1] = __builtin_amdgcn_mfma_f32_16x16x32_bf16(a0, b1, acc[0][1], 0, 0, 0);
            acc[1][1] = __builtin_amdgcn_mfma_f32_16x16x32_bf16(a1, b1, acc[1][1], 0, 0, 0);
        }
    }

    const int rj = lg * 4;
#pragma unroll
    for (int m = 0; m < 2; ++m) {
#pragma unroll
        for (int n = 0; n < 2; ++n) {
            int col = bx * 64 + wn * 32 + n * 16 + lo;
            float bias = dbias[e * HDIM + col];
#pragma unroll
            for (int j = 0; j < 4; ++j) {
                int sl = wm * 32 + m * 16 + rj + j;
                int slot = by * 128 + sl;
                if (slot < cnt) {
                    float val = (acc[m][n][j] + bias) * wts[sl];
                    tmp[((size_t)ksl[sl] * NTOK + toks[sl]) * HDIM + col] = val;
                }
            }
        }
    }
}

// ---------------- combine: out = tmp[0] + tmp[1] ----------------
__global__ __launch_bounds__(256) void combine_kernel(
    const float* __restrict__ tmp, float* __restrict__ out)
{
    int i = blockIdx.x * blockDim.x + threadIdx.x;
    const float4 a = ((const float4*)tmp)[i];
    const float4 b = ((const float4*)(tmp + (size_t)NTOK * HDIM))[i];
    float4 o;
    o.x = a.x + b.x; o.y = a.y + b.y; o.z = a.z + b.z; o.w = a.w + b.w;
    ((float4*)out)[i] = o;
}

extern "C" void kernel_launch(void* const* d_in, const int* in_sizes, int n_in,
                              void* d_out, int out_size, void* d_ws, size_t ws_size,
                              hipStream_t stream) {
    const float* flat  = (const float*)d_in[0];
    const float* rw    = (const float*)d_in[1];
    const float* gup   = (const float*)d_in[2];
    const float* gbias = (const float*)d_in[3];
    const float* dp    = (const float*)d_in[4];
    const float* dbias = (const float*)d_in[5];
    float* out    = (float*)d_out;
    float* scores = out + (size_t)NTOK * HDIM;

    char* ws = (char*)d_ws;
    int*   counts  = (int*)(ws + WS_COUNTS);
    int*   ltok    = (int*)(ws + WS_LTOK);
    int*   lkb     = (int*)(ws + WS_LK);
    float* lw      = (float*)(ws + WS_LW);
    unsigned short* xbf = (unsigned short*)(ws + WS_XBF);
    unsigned short* act = (unsigned short*)(ws + WS_ACT);
    float* tmp     = (float*)(ws + WS_TMP);
    unsigned short* w1t = (unsigned short*)(ws + WS_W1T);
    unsigned short* w2t = (unsigned short*)(ws + WS_W2T);

    hipMemsetAsync(counts, 0, 32, stream);
    router_kernel<<<NTOK, 64, 0, stream>>>(flat, rw, scores, counts, ltok, lkb, lw, xbf);
    transpose_bf16_kernel<<<dim3(NCOL / 64, HDIM / 64, NEXP), 256, 0, stream>>>(gup, w1t, HDIM, NCOL);
    transpose_bf16_kernel<<<dim3(HDIM / 64, IDIM / 64, NEXP), 256, 0, stream>>>(dp, w2t, IDIM, HDIM);
    gemm1_kernel<<<dim3(16, 8, NEXP), 512, 0, stream>>>(xbf, w1t, gbias, counts, ltok, act);
    gemm2_kernel<<<dim3(16, 8, NEXP), 512, 0, stream>>>(act, w2t, dbias, counts, ltok, lkb, lw, tmp);
    combine_kernel<<<1024, 256, 0, stream>>>(tmp, out);
}

// Round 7
// 102.002 us; speedup vs baseline: 1.4665x; 1.0400x over previous
//
#include <hip/hip_runtime.h>
#include <hip/hip_bf16.h>

typedef __attribute__((ext_vector_type(8))) short short8;
typedef __attribute__((ext_vector_type(4))) float f32x4;

#define NTOK 1024
#define HDIM 1024
#define IDIM 1024
#define NEXP 8
#define NCOL 2048  // 2*I interleaved gate/up

// ---- workspace layout (bytes) ----
#define WS_COUNTS   0
#define WS_LTOK     1024
#define WS_LW       (WS_LTOK + NEXP*NTOK*4)
#define WS_XBF      131072                                   // 1024x1024 bf16 = 2 MB
#define WS_ACT      (WS_XBF + NTOK*HDIM*2)                   // 2048x1024 bf16 = 4 MB
#define WS_W1T      (WS_ACT + 2*NTOK*IDIM*2)                 // 8x2048x1024 bf16 = 32 MB
#define WS_W2T      (WS_W1T + (size_t)NEXP*NCOL*HDIM*2)      // 8x1024x1024 bf16 = 16 MB

static __device__ __forceinline__ unsigned short f2bf(float x) {
    __hip_bfloat16 h = __float2bfloat16(x);   // RNE
    return __builtin_bit_cast(unsigned short, h);
}

#define GLDS16(g, l) __builtin_amdgcn_global_load_lds( \
    (const __attribute__((address_space(1))) void*)(g), \
    (__attribute__((address_space(3))) void*)(l), 16, 0, 0)

// ---------------- prep: router (top-2 lists, scores, Xbf) + both weight
// transposes (fp32 -> bf16, [e][k][c] -> [e][c][k]) in ONE launch.
// blocks [0,4096): gup transpose; [4096,6144): dp transpose; [6144,6400): router.
__global__ __launch_bounds__(256) void prep_kernel(
    const float* __restrict__ flat, const float* __restrict__ rw,
    const float* __restrict__ gup, const float* __restrict__ dp,
    float* __restrict__ scores, int* __restrict__ counts,
    int* __restrict__ ltok, float* __restrict__ lw,
    unsigned short* __restrict__ xbf,
    unsigned short* __restrict__ w1t, unsigned short* __restrict__ w2t)
{
    __shared__ float tile[64][65];
    const int b = blockIdx.x;
    const int t = threadIdx.x;

    if (b < 6144) {
        const float* src; unsigned short* dst; int nrows, ncols, e, rb, cb;
        if (b < 4096) {
            src = gup; dst = w1t; nrows = HDIM; ncols = NCOL;
            cb = b & 31; rb = (b >> 5) & 15; e = b >> 9;
        } else {
            int bb = b - 4096;
            src = dp; dst = w2t; nrows = IDIM; ncols = HDIM;
            cb = bb & 15; rb = (bb >> 4) & 15; e = bb >> 8;
        }
        {
            const int r0 = t >> 4, c4 = (t & 15) * 4;
#pragma unroll
            for (int p = 0; p < 4; ++p) {
                int r = p * 16 + r0;
                float4 v = *(const float4*)&src[((size_t)e * nrows + rb * 64 + r) * ncols + cb * 64 + c4];
                tile[r][c4 + 0] = v.x; tile[r][c4 + 1] = v.y;
                tile[r][c4 + 2] = v.z; tile[r][c4 + 3] = v.w;
            }
        }
        __syncthreads();
        {
            const int c0 = t >> 3, r8 = (t & 7) * 8;
#pragma unroll
            for (int p = 0; p < 2; ++p) {
                int c = p * 32 + c0;
                short8 o;
#pragma unroll
                for (int i = 0; i < 8; ++i) o[i] = (short)f2bf(tile[r8 + i][c]);
                *(short8*)&dst[((size_t)e * ncols + cb * 64 + c) * nrows + rb * 64 + r8] = o;
            }
        }
        return;
    }

    // ---- router: 4 waves/block, one token per wave ----
    const int n = (b - 6144) * 4 + (t >> 6);
    const int l = t & 63;
    float acc[NEXP];
#pragma unroll
    for (int e = 0; e < NEXP; ++e) acc[e] = 0.f;
    const float* xrow = flat + (size_t)n * HDIM;
#pragma unroll
    for (int j = 0; j < 4; ++j) {
        int h = j * 256 + l * 4;
        float4 v = *(const float4*)&xrow[h];
        ushort4 xb;
        xb.x = f2bf(v.x); xb.y = f2bf(v.y); xb.z = f2bf(v.z); xb.w = f2bf(v.w);
        *(ushort4*)&xbf[(size_t)n * HDIM + h] = xb;
#pragma unroll
        for (int e = 0; e < NEXP; ++e) {
            float4 wv = *(const float4*)&rw[e * HDIM + h];
            acc[e] += v.x * wv.x + v.y * wv.y + v.z * wv.z + v.w * wv.w;
        }
    }
#pragma unroll
    for (int e = 0; e < NEXP; ++e) {
#pragma unroll
        for (int off = 32; off > 0; off >>= 1)
            acc[e] += __shfl_down(acc[e], off);
    }
    if (l == 0) {
        float m = acc[0];
#pragma unroll
        for (int e = 1; e < NEXP; ++e) m = fmaxf(m, acc[e]);
        float s = 0.f, p[NEXP];
#pragma unroll
        for (int e = 0; e < NEXP; ++e) { p[e] = __expf(acc[e] - m); s += p[e]; }
        float inv = 1.f / s;
#pragma unroll
        for (int e = 0; e < NEXP; ++e) { p[e] *= inv; scores[n * NEXP + e] = p[e]; }
        int i0 = 0;
#pragma unroll
        for (int e = 1; e < NEXP; ++e) if (p[e] > p[i0]) i0 = e;
        int i1 = (i0 == 0) ? 1 : 0;
#pragma unroll
        for (int e = 0; e < NEXP; ++e) if (e != i0 && p[e] > p[i1]) i1 = e;
        int pos0 = atomicAdd(&counts[i0], 1);
        ltok[i0 * NTOK + pos0] = n; lw[i0 * NTOK + pos0] = p[i0];
        int pos1 = atomicAdd(&counts[i1], 1);
        ltok[i1 * NTOK + pos1] = n; lw[i1 * NTOK + pos1] = p[i1];
    }
}

// ---------------- GEMM1: act[slot][i] = f(Xbf[tok] @ W1t[e]) fused activation ----
// BM=128 x BN=128, BK=64, 512 thr / 8 waves (2x4), wave-tile 64x32 (acc 4x2).
// K-loop: two raw barriers + counted vmcnt (loads for t+1 never drained).
__global__ __launch_bounds__(512) void gemm1_kernel(
    const unsigned short* __restrict__ xbf, const unsigned short* __restrict__ w1t,
    const float* __restrict__ gbias,
    const int* __restrict__ counts,
    const int* __restrict__ ltok, unsigned short* __restrict__ act)
{
    const int e = blockIdx.z;
    int cnt = 0, off = 0;
#pragma unroll
    for (int j2 = 0; j2 < NEXP; ++j2) {
        int c = counts[j2];
        if (j2 < e) off += c;
        if (j2 == e) cnt = c;
    }
    const int by = blockIdx.y;
    if (by * 128 >= cnt) return;
    const int bx = blockIdx.x;
    const int t = threadIdx.x;
    const int l = t & 63, w = t >> 6;
    const int wm = w >> 2, wn = w & 3;

    __shared__ unsigned short As[2][128][64];
    __shared__ unsigned short Bs[2][128][64];
    __shared__ int toks[128];
    if (t < 128) toks[t] = ltok[e * NTOK + min(by * 128 + t, cnt - 1)];
    __syncthreads();

    const int li = l & 7, lr = l >> 3;
    const int kswz = (li ^ lr) * 8;
    const unsigned short* asrc[2];
    const unsigned short* bsrc[2];
#pragma unroll
    for (int j = 0; j < 2; ++j) {
        int rr = (w * 2 + j) * 8 + lr;
        asrc[j] = xbf + (size_t)toks[rr] * HDIM + kswz;
        bsrc[j] = w1t + ((size_t)e * NCOL + bx * 128 + rr) * HDIM + kswz;
    }

    f32x4 acc[4][2];
#pragma unroll
    for (int m = 0; m < 4; ++m)
#pragma unroll
        for (int n = 0; n < 2; ++n) acc[m][n] = 0.f;

    // prologue: issue loads(0)
#pragma unroll
    for (int j = 0; j < 2; ++j) {
        GLDS16(asrc[j], &As[0][(w * 2 + j) * 8][0]);
        GLDS16(bsrc[j], &Bs[0][(w * 2 + j) * 8][0]);
    }

    const int lg = l >> 4, lo = l & 15;
    const int cq0 = ((0 + lg) ^ (lo & 7)) * 8;
    const int cq1 = ((4 + lg) ^ (lo & 7)) * 8;

    for (int ks = 0; ks < HDIM / 64; ++ks) {
        const int p = ks & 1;
        __builtin_amdgcn_s_barrier();     // closes compute(ks-1): back buffer free
        if (ks + 1 < HDIM / 64) {
            const int kadv = (ks + 1) * 64;
#pragma unroll
            for (int j = 0; j < 2; ++j) {
                GLDS16(asrc[j] + kadv, &As[p ^ 1][(w * 2 + j) * 8][0]);
                GLDS16(bsrc[j] + kadv, &Bs[p ^ 1][(w * 2 + j) * 8][0]);
            }
            asm volatile("s_waitcnt vmcnt(4)" ::: "memory");  // own ks-loads done; ks+1 in flight
        } else {
            asm volatile("s_waitcnt vmcnt(0)" ::: "memory");
        }
        __builtin_amdgcn_sched_barrier(0);
        __builtin_amdgcn_s_barrier();     // all waves' ks-loads visible
#pragma unroll
        for (int q = 0; q < 2; ++q) {
            const int cq = q ? cq1 : cq0;
            short8 a0 = *(const short8*)&As[p][wm * 64 +  0 + lo][cq];
            short8 a1 = *(const short8*)&As[p][wm * 64 + 16 + lo][cq];
            short8 a2 = *(const short8*)&As[p][wm * 64 + 32 + lo][cq];
            short8 a3 = *(const short8*)&As[p][wm * 64 + 48 + lo][cq];
            short8 b0 = *(const short8*)&Bs[p][wn * 32 +  0 + lo][cq];
            short8 b1 = *(const short8*)&Bs[p][wn * 32 + 16 + lo][cq];
#pragma unroll
            for (int m = 0; m < 4; ++m) {
                short8 am = (m == 0) ? a0 : (m == 1) ? a1 : (m == 2) ? a2 : a3;
                acc[m][0] = __builtin_amdgcn_mfma_f32_16x16x32_bf16(am, b0, acc[m][0], 0, 0, 0);
                acc[m][1] = __builtin_amdgcn_mfma_f32_16x16x32_bf16(am, b1, acc[m][1], 0, 0, 0);
            }
        }
    }

    // epilogue: (gate,up) pairs live in adjacent lanes (col parity == lane parity)
    const int rj = lg * 4;
#pragma unroll
    for (int m = 0; m < 4; ++m) {
#pragma unroll
        for (int n = 0; n < 2; ++n) {
            int col = bx * 128 + wn * 32 + n * 16 + lo;
            float bias = gbias[e * NCOL + col];
#pragma unroll
            for (int j = 0; j < 4; ++j) {
                int slot = by * 128 + wm * 64 + m * 16 + rj + j;
                float val = acc[m][n][j] + bias;
                float other = __shfl_xor(val, 1);
                float g = (l & 1) ? other : val;
                float u = (l & 1) ? val : other;
                g = fminf(g, 7.f);
                u = fminf(fmaxf(u, -7.f), 7.f);
                float av = (u + 1.f) * g * (1.f / (1.f + __expf(-1.702f * g)));
                if (!(l & 1) && slot < cnt)
                    act[(size_t)(off + slot) * IDIM + (col >> 1)] = f2bf(av);
            }
        }
    }
}

// ---------------- GEMM2: out[tok][h] += (act @ W2t[e] + bias) * w  (atomic) ----
// BM=128 x BN=64, BK=64, 512 thr / 8 waves (4x2), wave-tile 32x32 (acc 2x2).
// Exactly 2 atomic adds per out element onto memset-zero: bitwise deterministic
// (0+a = a exactly; IEEE a+b is bitwise commutative).
__global__ __launch_bounds__(512) void gemm2_kernel(
    const unsigned short* __restrict__ act, const unsigned short* __restrict__ w2t,
    const float* __restrict__ dbias,
    const int* __restrict__ counts,
    const int* __restrict__ ltok,
    const float* __restrict__ lw, float* __restrict__ outbuf)
{
    const int e = blockIdx.z;
    int cnt = 0, off = 0;
#pragma unroll
    for (int j2 = 0; j2 < NEXP; ++j2) {
        int c = counts[j2];
        if (j2 < e) off += c;
        if (j2 == e) cnt = c;
    }
    const int by = blockIdx.y;
    if (by * 128 >= cnt) return;
    const int bx = blockIdx.x;
    const int t = threadIdx.x;
    const int l = t & 63, w = t >> 6;
    const int wm = w >> 1, wn = w & 1;

    __shared__ unsigned short As[2][128][64];
    __shared__ unsigned short Bs[2][64][64];
    __shared__ int toks[128];
    __shared__ float wts[128];
    if (t < 128) {
        int cl = min(by * 128 + t, cnt - 1);
        toks[t] = ltok[e * NTOK + cl];
        wts[t]  = lw[e * NTOK + cl];
    }
    __syncthreads();

    const int li = l & 7, lr = l >> 3;
    const int kswz = (li ^ lr) * 8;
    const unsigned short* asrc[2];
#pragma unroll
    for (int j = 0; j < 2; ++j) {
        int rr = (w * 2 + j) * 8 + lr;
        asrc[j] = act + (size_t)(off + min(by * 128 + rr, cnt - 1)) * IDIM + kswz;
    }
    const unsigned short* bsrc = w2t + ((size_t)e * HDIM + bx * 64 + w * 8 + lr) * IDIM + kswz;

    f32x4 acc[2][2];
#pragma unroll
    for (int m = 0; m < 2; ++m)
#pragma unroll
        for (int n = 0; n < 2; ++n) acc[m][n] = 0.f;

    // prologue: issue loads(0)
#pragma unroll
    for (int j = 0; j < 2; ++j)
        GLDS16(asrc[j], &As[0][(w * 2 + j) * 8][0]);
    GLDS16(bsrc, &Bs[0][w * 8][0]);

    const int lg = l >> 4, lo = l & 15;
    const int cq0 = ((0 + lg) ^ (lo & 7)) * 8;
    const int cq1 = ((4 + lg) ^ (lo & 7)) * 8;

    for (int ks = 0; ks < IDIM / 64; ++ks) {
        const int p = ks & 1;
        __builtin_amdgcn_s_barrier();
        if (ks + 1 < IDIM / 64) {
            const int kadv = (ks + 1) * 64;
#pragma unroll
            for (int j = 0; j < 2; ++j)
                GLDS16(asrc[j] + kadv, &As[p ^ 1][(w * 2 + j) * 8][0]);
            GLDS16(bsrc + kadv, &Bs[p ^ 1][w * 8][0]);
            asm volatile("s_waitcnt vmcnt(3)" ::: "memory");
        } else {
            asm volatile("s_waitcnt vmcnt(0)" ::: "memory");
        }
        __builtin_amdgcn_sched_barrier(0);
        __builtin_amdgcn_s_barrier();
#pragma unroll
        for (int q = 0; q < 2; ++q) {
            const int cq = q ? cq1 : cq0;
            short8 a0 = *(const short8*)&As[p][wm * 32 +  0 + lo][cq];
            short8 a1 = *(const short8*)&As[p][wm * 32 + 16 + lo][cq];
            short8 b0 = *(const short8*)&Bs[p][wn * 32 +  0 + lo][cq];
            short8 b1 = *(const short8*)&Bs[p][wn * 32 + 16 + lo][cq];
            acc[0][0] = __builtin_amdgcn_mfma_f32_16x16x32_bf16(a0, b0, acc[0][0], 0, 0, 0);
            acc[1][0] = __builtin_amdgcn_mfma_f32_16x16x32_bf16(a1, b0, acc[1][0], 0, 0, 0);
            acc[0][1] = __builtin_amdgcn_mfma_f32_16x16x32_bf16(a0, b1, acc[0][1], 0, 0, 0);
            acc[1][1] = __builtin_amdgcn_mfma_f32_16x16x32_bf16(a1, b1, acc[1][1], 0, 0, 0);
        }
    }

    const int rj = lg * 4;
#pragma unroll
    for (int m = 0; m < 2; ++m) {
#pragma unroll
        for (int n = 0; n < 2; ++n) {
            int col = bx * 64 + wn * 32 + n * 16 + lo;
            float bias = dbias[e * HDIM + col];
#pragma unroll
            for (int j = 0; j < 4; ++j) {
                int sl = wm * 32 + m * 16 + rj + j;
                int slot = by * 128 + sl;
                if (slot < cnt) {
                    float val = (acc[m][n][j] + bias) * wts[sl];
                    atomicAdd(&outbuf[(size_t)toks[sl] * HDIM + col], val);
                }
            }
        }
    }
}

extern "C" void kernel_launch(void* const* d_in, const int* in_sizes, int n_in,
                              void* d_out, int out_size, void* d_ws, size_t ws_size,
                              hipStream_t stream) {
    const float* flat  = (const float*)d_in[0];
    const float* rw    = (const float*)d_in[1];
    const float* gup   = (const float*)d_in[2];
    const float* gbias = (const float*)d_in[3];
    const float* dp    = (const float*)d_in[4];
    const float* dbias = (const float*)d_in[5];
    float* out    = (float*)d_out;
    float* scores = out + (size_t)NTOK * HDIM;

    char* ws = (char*)d_ws;
    int*   counts  = (int*)(ws + WS_COUNTS);
    int*   ltok    = (int*)(ws + WS_LTOK);
    float* lw      = (float*)(ws + WS_LW);
    unsigned short* xbf = (unsigned short*)(ws + WS_XBF);
    unsigned short* act = (unsigned short*)(ws + WS_ACT);
    unsigned short* w1t = (unsigned short*)(ws + WS_W1T);
    unsigned short* w2t = (unsigned short*)(ws + WS_W2T);

    hipMemsetAsync(counts, 0, 32, stream);
    hipMemsetAsync(out, 0, (size_t)NTOK * HDIM * sizeof(float), stream);
    prep_kernel<<<6400, 256, 0, stream>>>(flat, rw, gup, dp, scores, counts,
                                          ltok, lw, xbf, w1t, w2t);
    gemm1_kernel<<<dim3(16, 8, NEXP), 512, 0, stream>>>(xbf, w1t, gbias, counts, ltok, act);
    gemm2_kernel<<<dim3(16, 8, NEXP), 512, 0, stream>>>(act, w2t, dbias, counts, ltok, lw, out);
}